// Round 3
// baseline (1406.836 us; speedup 1.0000x reference)
//
#include <hip/hip_runtime.h>
#include <cstddef>

static constexpr int NX = 100000;
static constexpr int NC = 50000;
static constexpr int E  = 1000000;
static constexpr int E3 = 3 * E;

static constexpr int SHIFT = 7;                    // 128 dst-nodes per bucket
static constexpr int BUCK_NODES = 1 << SHIFT;
static constexpr int NB = (NX + BUCK_NODES - 1) / BUCK_NODES;   // 782
static constexpr int PF_CHUNK = 4096;              // edges per partition block (16/thread)

// ---------------- GEMM: out_l = [relu](in @ W_l^T + b_l), up to 3 layers ----------------
__global__ __launch_bounds__(256) void fused_linear(
    const float* __restrict__ in, int nrows,
    const float* __restrict__ W0, const float* __restrict__ b0, float* __restrict__ o0,
    const float* __restrict__ W1, const float* __restrict__ b1, float* __restrict__ o1,
    const float* __restrict__ W2, const float* __restrict__ b2, float* __restrict__ o2,
    int nlayers, int relu_mask)
{
    __shared__ float xT[64 * 68];
    __shared__ float Wt[64 * 68];
    __shared__ float bs[64];
    const int t  = threadIdx.x;
    const int tr = t >> 4;
    const int tc = t & 15;
    const int row0 = blockIdx.x * 64;

    #pragma unroll
    for (int p = 0; p < 4; ++p) {
        const int r   = p * 16 + tr;
        const int row = row0 + r;
        const int k4  = tc * 4;
        float4 v = make_float4(0.f, 0.f, 0.f, 0.f);
        if (row < nrows)
            v = *reinterpret_cast<const float4*>(in + (size_t)row * 64 + k4);
        xT[(k4 + 0) * 68 + r] = v.x;
        xT[(k4 + 1) * 68 + r] = v.y;
        xT[(k4 + 2) * 68 + r] = v.z;
        xT[(k4 + 3) * 68 + r] = v.w;
    }

    for (int l = 0; l < nlayers; ++l) {
        const float* W = (l == 0) ? W0 : (l == 1) ? W1 : W2;
        const float* b = (l == 0) ? b0 : (l == 1) ? b1 : b2;
        float*       o = (l == 0) ? o0 : (l == 1) ? o1 : o2;
        if (l) __syncthreads();
        #pragma unroll
        for (int p = 0; p < 4; ++p) {
            const int j  = p * 16 + tr;
            const int k4 = tc * 4;
            float4 v = *reinterpret_cast<const float4*>(W + j * 64 + k4);
            Wt[(k4 + 0) * 68 + j] = v.x;
            Wt[(k4 + 1) * 68 + j] = v.y;
            Wt[(k4 + 2) * 68 + j] = v.z;
            Wt[(k4 + 3) * 68 + j] = v.w;
        }
        if (t < 64) bs[t] = b[t];
        __syncthreads();

        float acc[4][4];
        #pragma unroll
        for (int i = 0; i < 4; ++i)
            #pragma unroll
            for (int j = 0; j < 4; ++j) acc[i][j] = 0.f;

        #pragma unroll 8
        for (int k = 0; k < 64; ++k) {
            const float4 xv = *reinterpret_cast<const float4*>(&xT[k * 68 + tr * 4]);
            const float4 wv = *reinterpret_cast<const float4*>(&Wt[k * 68 + tc * 4]);
            const float xa[4] = {xv.x, xv.y, xv.z, xv.w};
            const float wa[4] = {wv.x, wv.y, wv.z, wv.w};
            #pragma unroll
            for (int i = 0; i < 4; ++i)
                #pragma unroll
                for (int j = 0; j < 4; ++j)
                    acc[i][j] = fmaf(xa[i], wa[j], acc[i][j]);
        }

        const bool relu = (relu_mask >> l) & 1;
        #pragma unroll
        for (int i = 0; i < 4; ++i) {
            const int row = row0 + tr * 4 + i;
            if (row < nrows) {
                float4 ov;
                ov.x = acc[i][0] + bs[tc * 4 + 0];
                ov.y = acc[i][1] + bs[tc * 4 + 1];
                ov.z = acc[i][2] + bs[tc * 4 + 2];
                ov.w = acc[i][3] + bs[tc * 4 + 3];
                if (relu) {
                    ov.x = fmaxf(ov.x, 0.f);
                    ov.y = fmaxf(ov.y, 0.f);
                    ov.z = fmaxf(ov.z, 0.f);
                    ov.w = fmaxf(ov.w, 0.f);
                }
                *reinterpret_cast<float4*>(o + (size_t)row * 64 + tc * 4) = ov;
            }
        }
    }
}

// ---------------- bucket pipeline ----------------
__global__ __launch_bounds__(256) void zero_ints(int* __restrict__ p, int n)
{
    int i = blockIdx.x * 256 + threadIdx.x;
    if (i < n) p[i] = 0;
}

__global__ __launch_bounds__(256) void bucket_count(
    const int* __restrict__ efd, const int* __restrict__ ebs, const int* __restrict__ ecd,
    int* __restrict__ bcnt)
{
    __shared__ int h[NB];
    for (int i = threadIdx.x; i < NB; i += 256) h[i] = 0;
    __syncthreads();
    for (int e = blockIdx.x * 256 + threadIdx.x; e < E3; e += gridDim.x * 256) {
        int d;
        if (e < E)          d = efd[e];
        else if (e < 2 * E) d = ebs[e - E];       // '<-' edge: target is stored src
        else                d = ecd[e - 2 * E];
        atomicAdd(&h[d >> SHIFT], 1);
    }
    __syncthreads();
    for (int i = threadIdx.x; i < NB; i += 256)
        if (h[i]) atomicAdd(&bcnt[i], h[i]);
}

__global__ __launch_bounds__(1024) void scan_buckets(
    const int* __restrict__ bcnt, int* __restrict__ bstart, int* __restrict__ bcursor)
{
    __shared__ int s[1024];
    const int v = (threadIdx.x < NB) ? bcnt[threadIdx.x] : 0;
    s[threadIdx.x] = v;
    __syncthreads();
    for (int st = 1; st < 1024; st <<= 1) {
        int t = (threadIdx.x >= st) ? s[threadIdx.x - st] : 0;
        __syncthreads();
        s[threadIdx.x] += t;
        __syncthreads();
    }
    if (threadIdx.x < NB) {
        const int excl = s[threadIdx.x] - v;
        bstart[threadIdx.x]  = excl;
        bcursor[threadIdx.x] = excl;
    }
    if (threadIdx.x == 0) bstart[NB] = E3;
}

// Block-aggregated partition: one global atomic per (block,bucket), contiguous
// sub-segment per block -> line-friendly writes. pk = (src_global << SHIFT) | dst_local.
__global__ __launch_bounds__(256) void partition_fill(
    const int* __restrict__ efs, const int* __restrict__ efd,
    const int* __restrict__ ebs, const int* __restrict__ ebd,
    const int* __restrict__ ecs, const int* __restrict__ ecd,
    int* __restrict__ bcursor, unsigned* __restrict__ pk)
{
    __shared__ int h[NB];
    __shared__ int base[NB];
    for (int i = threadIdx.x; i < NB; i += 256) h[i] = 0;
    __syncthreads();
    const int e0 = blockIdx.x * PF_CHUNK;
    unsigned pack[16];
    int buck[16], rank[16];
    #pragma unroll
    for (int i = 0; i < 16; ++i) {
        const int e = e0 + i * 256 + threadIdx.x;
        buck[i] = -1;
        if (e < E3) {
            int d, sg;
            if (e < E)          { d = efd[e];         sg = efs[e]; }
            else if (e < 2 * E) { d = ebs[e - E];     sg = NX + ebd[e - E]; }      // swap
            else                { d = ecd[e - 2 * E]; sg = 2 * NX + ecs[e - 2 * E]; }
            buck[i] = d >> SHIFT;
            pack[i] = ((unsigned)sg << SHIFT) | (unsigned)(d & (BUCK_NODES - 1));
            rank[i] = atomicAdd(&h[buck[i]], 1);
        }
    }
    __syncthreads();
    for (int b = threadIdx.x; b < NB; b += 256)
        base[b] = h[b] ? atomicAdd(&bcursor[b], h[b]) : 0;
    __syncthreads();
    #pragma unroll
    for (int i = 0; i < 16; ++i)
        if (buck[i] >= 0) pk[base[buck[i]] + rank[i]] = pack[i];
}

// One block per bucket: LDS accumulator [128 nodes][64 feat], wave-per-edge,
// unroll-4 for outstanding loads; then agg[node] = self_x(already there) + acc.
__global__ __launch_bounds__(256) void bucket_aggregate(
    const int* __restrict__ bstart, const unsigned* __restrict__ pk,
    const float* __restrict__ h_all, float* __restrict__ agg)
{
    __shared__ float acc[BUCK_NODES * 64];    // 32 KB
    for (int i = threadIdx.x; i < BUCK_NODES * 64; i += 256) acc[i] = 0.f;
    __syncthreads();

    const int b    = blockIdx.x;
    const int s    = bstart[b];
    const int t    = bstart[b + 1];
    const int wv   = threadIdx.x >> 6;
    const int lane = threadIdx.x & 63;

    int e = s + wv;
    for (; e + 12 < t; e += 16) {
        const unsigned p0 = pk[e], p1 = pk[e + 4], p2 = pk[e + 8], p3 = pk[e + 12];
        const float v0 = h_all[(size_t)(p0 >> SHIFT) * 64 + lane];
        const float v1 = h_all[(size_t)(p1 >> SHIFT) * 64 + lane];
        const float v2 = h_all[(size_t)(p2 >> SHIFT) * 64 + lane];
        const float v3 = h_all[(size_t)(p3 >> SHIFT) * 64 + lane];
        atomicAdd(&acc[(p0 & (BUCK_NODES - 1)) * 64 + lane], v0);
        atomicAdd(&acc[(p1 & (BUCK_NODES - 1)) * 64 + lane], v1);
        atomicAdd(&acc[(p2 & (BUCK_NODES - 1)) * 64 + lane], v2);
        atomicAdd(&acc[(p3 & (BUCK_NODES - 1)) * 64 + lane], v3);
    }
    for (; e < t; e += 4) {
        const unsigned p = pk[e];
        const float v = h_all[(size_t)(p >> SHIFT) * 64 + lane];
        atomicAdd(&acc[(p & (BUCK_NODES - 1)) * 64 + lane], v);
    }
    __syncthreads();

    const int n0 = b << SHIFT;
    for (int i4 = threadIdx.x; i4 < BUCK_NODES * 16; i4 += 256) {
        const int node = n0 + (i4 >> 4);
        if (node < NX) {
            float4* dst = reinterpret_cast<float4*>(agg) + (size_t)n0 * 16 + i4;
            float4 a = *dst;
            const float4 v = *reinterpret_cast<const float4*>(acc + (size_t)i4 * 4);
            a.x += v.x; a.y += v.y; a.z += v.z; a.w += v.w;
            *dst = a;
        }
    }
}

// fallback: per-edge global atomics (round-1 path)
__global__ __launch_bounds__(256) void scatter_edges(
    const int* __restrict__ efs, const int* __restrict__ efd,
    const int* __restrict__ ebs, const int* __restrict__ ebd,
    const int* __restrict__ ecs, const int* __restrict__ ecd,
    const float* __restrict__ hff, const float* __restrict__ hbb,
    const float* __restrict__ hcx, float* __restrict__ agg)
{
    const int idx  = blockIdx.x * 256 + threadIdx.x;
    const int lane = idx & 63;
    const int e    = idx >> 6;
    if (e >= E3) return;
    const int type = e / E;
    const int ei   = e - type * E;
    int src, dst;
    const float* h;
    if (type == 0)      { src = efs[ei]; dst = efd[ei]; h = hff; }
    else if (type == 1) { src = ebd[ei]; dst = ebs[ei]; h = hbb; }
    else                { src = ecs[ei]; dst = ecd[ei]; h = hcx; }
    atomicAdd(&agg[(size_t)dst * 64 + lane], h[(size_t)src * 64 + lane]);
}

extern "C" void kernel_launch(void* const* d_in, const int* in_sizes, int n_in,
                              void* d_out, int out_size, void* d_ws, size_t ws_size,
                              hipStream_t stream)
{
    const float* x   = (const float*)d_in[0];
    const float* c   = (const float*)d_in[1];
    const int*   efs = (const int*)d_in[2];
    const int*   efd = (const int*)d_in[3];
    const int*   ebs = (const int*)d_in[4];
    const int*   ebd = (const int*)d_in[5];
    const int*   ecs = (const int*)d_in[6];
    const int*   ecd = (const int*)d_in[7];
    const float* Wx  = (const float*)d_in[8];
    const float* bx  = (const float*)d_in[9];
    const float* Wc  = (const float*)d_in[10];
    const float* bc  = (const float*)d_in[11];
    const float* Wff = (const float*)d_in[12];
    const float* bff = (const float*)d_in[13];
    const float* Wbb = (const float*)d_in[14];
    const float* bbb = (const float*)d_in[15];
    const float* Wcx = (const float*)d_in[16];
    const float* bcx = (const float*)d_in[17];
    const float* Wp  = (const float*)d_in[18];
    const float* bp  = (const float*)d_in[19];

    float* out_x = (float*)d_out;                    // [NX*64]; also agg buffer
    float* out_c = (float*)d_out + (size_t)NX * 64;  // [NC*64]

    float* h_all = (float*)d_ws;                     // rows: [0,NX)=hff, [NX,2NX)=hbb, [2NX,..)=hcx
    float* hff = h_all;
    float* hbb = h_all + (size_t)NX * 64;
    float* hcx = h_all + (size_t)2 * NX * 64;
    const size_t h_floats = (size_t)(2 * NX + NC) * 64;

    int* bcnt    = (int*)(h_all + h_floats);         // NB
    int* bstart  = bcnt + NB;                        // NB+1
    int* bcursor = bstart + NB + 1;                  // NB
    unsigned* pk = (unsigned*)(bcursor + NB);        // E3
    const size_t need_bytes = h_floats * 4 + ((size_t)3 * NB + 1 + (size_t)E3) * 4;

    // node GEMMs
    fused_linear<<<(NX + 63) / 64, 256, 0, stream>>>(
        x, NX, Wx, bx, out_x, Wff, bff, hff, Wbb, bbb, hbb, 3, 7);
    fused_linear<<<(NC + 63) / 64, 256, 0, stream>>>(
        c, NC, Wc, bc, out_c, Wcx, bcx, hcx, nullptr, nullptr, nullptr, 2, 3);

    if (ws_size >= need_bytes) {
        zero_ints<<<(NB + 255) / 256, 256, 0, stream>>>(bcnt, NB);
        bucket_count<<<384, 256, 0, stream>>>(efd, ebs, ecd, bcnt);
        scan_buckets<<<1, 1024, 0, stream>>>(bcnt, bstart, bcursor);
        partition_fill<<<(E3 + PF_CHUNK - 1) / PF_CHUNK, 256, 0, stream>>>(
            efs, efd, ebs, ebd, ecs, ecd, bcursor, pk);
        bucket_aggregate<<<NB, 256, 0, stream>>>(bstart, pk, h_all, out_x);
    } else {
        scatter_edges<<<((size_t)E3 * 64 + 255) / 256, 256, 0, stream>>>(
            efs, efd, ebs, ebd, ecs, ecd, hff, hbb, hcx, out_x);
    }

    // pool GEMM in-place on agg -> out_x
    fused_linear<<<(NX + 63) / 64, 256, 0, stream>>>(
        out_x, NX, Wp, bp, out_x, nullptr, nullptr, nullptr, nullptr, nullptr, nullptr, 1, 0);
}

// Round 4
// 225.399 us; speedup vs baseline: 6.2415x; 6.2415x over previous
//
#include <hip/hip_runtime.h>
#include <cstddef>

typedef unsigned short ushort_t;

static constexpr int NX = 100000;
static constexpr int NC = 50000;
static constexpr int E  = 1000000;
static constexpr int E3 = 3 * E;

static constexpr int SHIFT = 8;                               // 256 dst-nodes per bucket
static constexpr int BUCK_NODES = 1 << SHIFT;
static constexpr int NB = (NX + BUCK_NODES - 1) / BUCK_NODES; // 391
static constexpr int CAP = 8448;                              // mean 7673 + 8.8 sigma
static constexpr int PF_CHUNK = 4096;                         // edges per partition block

__device__ inline ushort_t f2bf(float f) {
    unsigned u = __float_as_uint(f);
    return (ushort_t)((u + 0x7fffu + ((u >> 16) & 1u)) >> 16);   // RNE
}

// ---------------- GEMM: out_l = [relu](in @ W_l^T + b_l), up to 3 layers ----------------
// bf16_mask bit l: store layer-l output as bf16 (ushort) instead of f32.
__global__ __launch_bounds__(256) void fused_linear(
    const float* __restrict__ in, int nrows,
    const float* __restrict__ W0, const float* __restrict__ b0, void* __restrict__ o0,
    const float* __restrict__ W1, const float* __restrict__ b1, void* __restrict__ o1,
    const float* __restrict__ W2, const float* __restrict__ b2, void* __restrict__ o2,
    int nlayers, int relu_mask, int bf16_mask)
{
    __shared__ float xT[64 * 68];
    __shared__ float Wt[64 * 68];
    __shared__ float bs[64];
    const int t  = threadIdx.x;
    const int tr = t >> 4;
    const int tc = t & 15;
    const int row0 = blockIdx.x * 64;

    #pragma unroll
    for (int p = 0; p < 4; ++p) {
        const int r   = p * 16 + tr;
        const int row = row0 + r;
        const int k4  = tc * 4;
        float4 v = make_float4(0.f, 0.f, 0.f, 0.f);
        if (row < nrows)
            v = *reinterpret_cast<const float4*>(in + (size_t)row * 64 + k4);
        xT[(k4 + 0) * 68 + r] = v.x;
        xT[(k4 + 1) * 68 + r] = v.y;
        xT[(k4 + 2) * 68 + r] = v.z;
        xT[(k4 + 3) * 68 + r] = v.w;
    }

    for (int l = 0; l < nlayers; ++l) {
        const float* W = (l == 0) ? W0 : (l == 1) ? W1 : W2;
        const float* b = (l == 0) ? b0 : (l == 1) ? b1 : b2;
        void*        o = (l == 0) ? o0 : (l == 1) ? o1 : o2;
        if (l) __syncthreads();
        #pragma unroll
        for (int p = 0; p < 4; ++p) {
            const int j  = p * 16 + tr;
            const int k4 = tc * 4;
            float4 v = *reinterpret_cast<const float4*>(W + j * 64 + k4);
            Wt[(k4 + 0) * 68 + j] = v.x;
            Wt[(k4 + 1) * 68 + j] = v.y;
            Wt[(k4 + 2) * 68 + j] = v.z;
            Wt[(k4 + 3) * 68 + j] = v.w;
        }
        if (t < 64) bs[t] = b[t];
        __syncthreads();

        float acc[4][4];
        #pragma unroll
        for (int i = 0; i < 4; ++i)
            #pragma unroll
            for (int j = 0; j < 4; ++j) acc[i][j] = 0.f;

        #pragma unroll 8
        for (int k = 0; k < 64; ++k) {
            const float4 xv = *reinterpret_cast<const float4*>(&xT[k * 68 + tr * 4]);
            const float4 wv = *reinterpret_cast<const float4*>(&Wt[k * 68 + tc * 4]);
            const float xa[4] = {xv.x, xv.y, xv.z, xv.w};
            const float wa[4] = {wv.x, wv.y, wv.z, wv.w};
            #pragma unroll
            for (int i = 0; i < 4; ++i)
                #pragma unroll
                for (int j = 0; j < 4; ++j)
                    acc[i][j] = fmaf(xa[i], wa[j], acc[i][j]);
        }

        const bool relu = (relu_mask >> l) & 1;
        const bool bf16 = (bf16_mask >> l) & 1;
        #pragma unroll
        for (int i = 0; i < 4; ++i) {
            const int row = row0 + tr * 4 + i;
            if (row < nrows) {
                float4 ov;
                ov.x = acc[i][0] + bs[tc * 4 + 0];
                ov.y = acc[i][1] + bs[tc * 4 + 1];
                ov.z = acc[i][2] + bs[tc * 4 + 2];
                ov.w = acc[i][3] + bs[tc * 4 + 3];
                if (relu) {
                    ov.x = fmaxf(ov.x, 0.f);
                    ov.y = fmaxf(ov.y, 0.f);
                    ov.z = fmaxf(ov.z, 0.f);
                    ov.w = fmaxf(ov.w, 0.f);
                }
                if (bf16) {
                    ushort_t* ob = (ushort_t*)o + (size_t)row * 64 + tc * 4;
                    ushort4 o16;
                    o16.x = f2bf(ov.x); o16.y = f2bf(ov.y);
                    o16.z = f2bf(ov.z); o16.w = f2bf(ov.w);
                    *reinterpret_cast<ushort4*>(ob) = o16;
                } else {
                    *reinterpret_cast<float4*>((float*)o + (size_t)row * 64 + tc * 4) = ov;
                }
            }
        }
    }
}

// ---------------- bucket pipeline (fixed-capacity segments, no count/scan) ----------------
__global__ __launch_bounds__(256) void init_cursor(int* __restrict__ bcursor)
{
    int i = blockIdx.x * 256 + threadIdx.x;
    if (i < NB) bcursor[i] = i * CAP;
}

// Block-aggregated partition: one global atomic per (block,bucket); contiguous
// per-block sub-segments. pk = (src_global << SHIFT) | dst_local.
__global__ __launch_bounds__(256) void partition_fill(
    const int* __restrict__ efs, const int* __restrict__ efd,
    const int* __restrict__ ebs, const int* __restrict__ ebd,
    const int* __restrict__ ecs, const int* __restrict__ ecd,
    int* __restrict__ bcursor, unsigned* __restrict__ pk)
{
    __shared__ int h[NB];
    __shared__ int base[NB];
    for (int i = threadIdx.x; i < NB; i += 256) h[i] = 0;
    __syncthreads();
    const int e0 = blockIdx.x * PF_CHUNK;
    unsigned pack[16];
    int buck[16], rank[16];
    #pragma unroll
    for (int i = 0; i < 16; ++i) {
        const int e = e0 + i * 256 + threadIdx.x;
        buck[i] = -1;
        if (e < E3) {
            int d, sg;
            if (e < E)          { d = efd[e];         sg = efs[e]; }
            else if (e < 2 * E) { d = ebs[e - E];     sg = NX + ebd[e - E]; }      // '<-': swap
            else                { d = ecd[e - 2 * E]; sg = 2 * NX + ecs[e - 2 * E]; }
            buck[i] = d >> SHIFT;
            pack[i] = ((unsigned)sg << SHIFT) | (unsigned)(d & (BUCK_NODES - 1));
            rank[i] = atomicAdd(&h[buck[i]], 1);
        }
    }
    __syncthreads();
    for (int b = threadIdx.x; b < NB; b += 256)
        base[b] = h[b] ? atomicAdd(&bcursor[b], h[b]) : 0;
    __syncthreads();
    #pragma unroll
    for (int i = 0; i < 16; ++i)
        if (buck[i] >= 0) pk[base[buck[i]] + rank[i]] = pack[i];
}

// One block per bucket: counting sort by dst-local -> srt (global src row ids),
// and per-node (start,count) segments.
__global__ __launch_bounds__(256) void node_sort(
    const int* __restrict__ bcursor, const unsigned* __restrict__ pk,
    int* __restrict__ srt, int2* __restrict__ nodeseg)
{
    __shared__ int cnt[BUCK_NODES];
    __shared__ int cur[BUCK_NODES];
    const int b = blockIdx.x;
    const int s = b * CAP;
    const int t = bcursor[b];
    cnt[threadIdx.x] = 0;
    __syncthreads();
    for (int e = s + threadIdx.x; e < t; e += 256)
        atomicAdd(&cnt[pk[e] & (BUCK_NODES - 1)], 1);
    __syncthreads();
    if (threadIdx.x == 0) {
        int run = s;
        for (int i = 0; i < BUCK_NODES; ++i) { cur[i] = run; run += cnt[i]; }
    }
    __syncthreads();
    const int node = (b << SHIFT) + threadIdx.x;
    const int my_start = cur[threadIdx.x];
    const int my_cnt   = cnt[threadIdx.x];
    __syncthreads();                      // reads of cur done before pass-2 mutates it
    if (node < NX) nodeseg[node] = make_int2(my_start, my_cnt);
    for (int e = s + threadIdx.x; e < t; e += 256) {
        const unsigned p = pk[e];
        const int pos = atomicAdd(&cur[p & (BUCK_NODES - 1)], 1);
        srt[pos] = (int)(p >> SHIFT);
    }
}

// One wave per dst node. Half-wave q (32 lanes) handles edges start+q, start+q+2, ...
// Each lane covers 2 features via packed bf16x2. agg already holds self_x (f32).
__global__ __launch_bounds__(256) void gather_agg_bf16(
    const int2* __restrict__ nodeseg, const int* __restrict__ srt,
    const ushort_t* __restrict__ h_bf, float* __restrict__ agg)
{
    const int wid = (blockIdx.x * 256 + threadIdx.x) >> 6;
    if (wid >= NX) return;
    const int lane = threadIdx.x & 63;
    const int half = lane >> 5;
    const int fl   = lane & 31;
    const int2 seg = nodeseg[wid];
    const int end  = seg.x + seg.y;
    float ax = 0.f, ay = 0.f;
    int e = seg.x + half;
    for (; e + 6 < end; e += 8) {
        const int s0 = srt[e], s1 = srt[e + 2], s2 = srt[e + 4], s3 = srt[e + 6];
        const unsigned u0 = *reinterpret_cast<const unsigned*>(h_bf + (size_t)s0 * 64 + fl * 2);
        const unsigned u1 = *reinterpret_cast<const unsigned*>(h_bf + (size_t)s1 * 64 + fl * 2);
        const unsigned u2 = *reinterpret_cast<const unsigned*>(h_bf + (size_t)s2 * 64 + fl * 2);
        const unsigned u3 = *reinterpret_cast<const unsigned*>(h_bf + (size_t)s3 * 64 + fl * 2);
        ax += __uint_as_float(u0 << 16) + __uint_as_float(u1 << 16)
            + __uint_as_float(u2 << 16) + __uint_as_float(u3 << 16);
        ay += __uint_as_float(u0 & 0xffff0000u) + __uint_as_float(u1 & 0xffff0000u)
            + __uint_as_float(u2 & 0xffff0000u) + __uint_as_float(u3 & 0xffff0000u);
    }
    for (; e < end; e += 2) {
        const unsigned u = *reinterpret_cast<const unsigned*>(h_bf + (size_t)srt[e] * 64 + fl * 2);
        ax += __uint_as_float(u << 16);
        ay += __uint_as_float(u & 0xffff0000u);
    }
    ax += __shfl_xor(ax, 32, 64);
    ay += __shfl_xor(ay, 32, 64);
    if (half == 0) {
        float2* p = reinterpret_cast<float2*>(agg + (size_t)wid * 64) + fl;
        float2 v = *p;
        v.x += ax; v.y += ay;
        *p = v;
    }
}

// fallback: per-edge global atomics on f32 agg, bf16 h
__global__ __launch_bounds__(256) void scatter_edges(
    const int* __restrict__ efs, const int* __restrict__ efd,
    const int* __restrict__ ebs, const int* __restrict__ ebd,
    const int* __restrict__ ecs, const int* __restrict__ ecd,
    const ushort_t* __restrict__ h_all, float* __restrict__ agg)
{
    const int idx  = blockIdx.x * 256 + threadIdx.x;
    const int lane = idx & 63;
    const int e    = idx >> 6;
    if (e >= E3) return;
    int src, dst;
    if (e < E)          { src = efs[e];           dst = efd[e]; }
    else if (e < 2 * E) { src = NX + ebd[e - E];  dst = ebs[e - E]; }
    else                { src = 2 * NX + ecs[e - 2 * E]; dst = ecd[e - 2 * E]; }
    const unsigned u = (unsigned)h_all[(size_t)src * 64 + lane] << 16;
    atomicAdd(&agg[(size_t)dst * 64 + lane], __uint_as_float(u));
}

extern "C" void kernel_launch(void* const* d_in, const int* in_sizes, int n_in,
                              void* d_out, int out_size, void* d_ws, size_t ws_size,
                              hipStream_t stream)
{
    const float* x   = (const float*)d_in[0];
    const float* c   = (const float*)d_in[1];
    const int*   efs = (const int*)d_in[2];
    const int*   efd = (const int*)d_in[3];
    const int*   ebs = (const int*)d_in[4];
    const int*   ebd = (const int*)d_in[5];
    const int*   ecs = (const int*)d_in[6];
    const int*   ecd = (const int*)d_in[7];
    const float* Wx  = (const float*)d_in[8];
    const float* bx  = (const float*)d_in[9];
    const float* Wc  = (const float*)d_in[10];
    const float* bc  = (const float*)d_in[11];
    const float* Wff = (const float*)d_in[12];
    const float* bff = (const float*)d_in[13];
    const float* Wbb = (const float*)d_in[14];
    const float* bbb = (const float*)d_in[15];
    const float* Wcx = (const float*)d_in[16];
    const float* bcx = (const float*)d_in[17];
    const float* Wp  = (const float*)d_in[18];
    const float* bp  = (const float*)d_in[19];

    float* out_x = (float*)d_out;                    // [NX*64]; also agg buffer
    float* out_c = (float*)d_out + (size_t)NX * 64;  // [NC*64]

    // ws layout: bf16 h table, then int2 nodeseg, then ints
    ushort_t* h_all = (ushort_t*)d_ws;               // rows: [0,NX)=hff, [NX,2NX)=hbb, [2NX,..)=hcx
    ushort_t* hff = h_all;
    ushort_t* hbb = h_all + (size_t)NX * 64;
    ushort_t* hcx = h_all + (size_t)2 * NX * 64;
    const size_t h_elems = (size_t)(2 * NX + NC) * 64;        // 16M bf16 = 32MB

    int2* nodeseg = (int2*)(h_all + h_elems);                 // NX
    int*  bcursor = (int*)(nodeseg + NX);                     // NB
    unsigned* pk  = (unsigned*)(bcursor + NB);                // NB*CAP
    int*  srt     = (int*)(pk + (size_t)NB * CAP);            // NB*CAP
    const size_t need_bytes = h_elems * 2 + (size_t)NX * 8 +
                              ((size_t)NB + 2 * (size_t)NB * CAP) * 4;

    // node GEMMs: agg=self_x (f32), h tables (bf16)
    fused_linear<<<(NX + 63) / 64, 256, 0, stream>>>(
        x, NX, Wx, bx, out_x, Wff, bff, hff, Wbb, bbb, hbb, 3, 7, 6);
    fused_linear<<<(NC + 63) / 64, 256, 0, stream>>>(
        c, NC, Wc, bc, out_c, Wcx, bcx, hcx, nullptr, nullptr, nullptr, 2, 3, 2);

    if (ws_size >= need_bytes) {
        init_cursor<<<(NB + 255) / 256, 256, 0, stream>>>(bcursor);
        partition_fill<<<(E3 + PF_CHUNK - 1) / PF_CHUNK, 256, 0, stream>>>(
            efs, efd, ebs, ebd, ecs, ecd, bcursor, pk);
        node_sort<<<NB, BUCK_NODES, 0, stream>>>(bcursor, pk, srt, nodeseg);
        gather_agg_bf16<<<((size_t)NX * 64 + 255) / 256, 256, 0, stream>>>(
            nodeseg, srt, h_all, out_x);
    } else {
        scatter_edges<<<((size_t)E3 * 64 + 255) / 256, 256, 0, stream>>>(
            efs, efd, ebs, ebd, ecs, ecd, h_all, out_x);
    }

    // pool GEMM in-place on agg -> out_x (f32 in / f32 out)
    fused_linear<<<(NX + 63) / 64, 256, 0, stream>>>(
        out_x, NX, Wp, bp, out_x, nullptr, nullptr, nullptr, nullptr, nullptr, nullptr, 1, 0, 0);
}

// Round 5
// 214.536 us; speedup vs baseline: 6.5576x; 1.0506x over previous
//
#include <hip/hip_runtime.h>
#include <cstddef>

typedef unsigned short ushort_t;
using f32x4  = __attribute__((ext_vector_type(4))) float;
using bf16x8 = __attribute__((ext_vector_type(8))) short;

static constexpr int NX = 100000;
static constexpr int NC = 50000;
static constexpr int E  = 1000000;
static constexpr int E3 = 3 * E;

static constexpr int SHIFT = 8;                               // 256 dst-nodes per bucket
static constexpr int BUCK_NODES = 1 << SHIFT;
static constexpr int NB = (NX + BUCK_NODES - 1) / BUCK_NODES; // 391
static constexpr int CAP = 8448;                              // mean 7673 + 8.8 sigma
static constexpr int PF_CHUNK = 4096;                         // edges per partition block

__device__ inline ushort_t f2bf(float f) {
    unsigned u = __float_as_uint(f);
    return (ushort_t)((u + 0x7fffu + ((u >> 16) & 1u)) >> 16);   // RNE
}

__device__ inline bf16x8 cvt8(float4 lo, float4 hi) {
    bf16x8 v;
    v[0] = (short)f2bf(lo.x); v[1] = (short)f2bf(lo.y);
    v[2] = (short)f2bf(lo.z); v[3] = (short)f2bf(lo.w);
    v[4] = (short)f2bf(hi.x); v[5] = (short)f2bf(hi.y);
    v[6] = (short)f2bf(hi.z); v[7] = (short)f2bf(hi.w);
    return v;
}

// ---------------- MFMA GEMM: out_l = [relu](in @ W_l^T + b_l), up to 3 layers ----------------
// 64-row tile/block, 4 waves, each wave owns a 32x32 output quadrant.
// A-frag: lane l, reg r -> in[row0+16m+(l&15)][ks*32+(l>>4)*8+r]  (8 contiguous f32)
// B-frag: lane l, reg r -> W [col0+16n+(l&15)][ks*32+(l>>4)*8+r]  (8 contiguous f32)
// C/D   : col = l&15, row = (l>>4)*4 + reg   (m89-verified)
__global__ __launch_bounds__(256) void fused_linear_mfma(
    const float* __restrict__ in, int nrows,
    const float* __restrict__ W0, const float* __restrict__ b0, void* __restrict__ o0,
    const float* __restrict__ W1, const float* __restrict__ b1, void* __restrict__ o1,
    const float* __restrict__ W2, const float* __restrict__ b2, void* __restrict__ o2,
    int nlayers, int relu_mask, int bf16_mask)
{
    const int t   = threadIdx.x;
    const int w   = t >> 6;
    const int l   = t & 63;
    const int lr  = l & 15;
    const int lk  = (l >> 4) * 8;
    const int row0 = blockIdx.x * 64 + (w >> 1) * 32;
    const int col0 = (w & 1) * 32;

    bf16x8 a[2][2];   // [m][ks]
    #pragma unroll
    for (int m = 0; m < 2; ++m) {
        #pragma unroll
        for (int ks = 0; ks < 2; ++ks) {
            const int row = row0 + 16 * m + lr;
            float4 lo = make_float4(0.f, 0.f, 0.f, 0.f), hi = lo;
            if (row < nrows) {
                const float* p = in + (size_t)row * 64 + ks * 32 + lk;
                lo = *reinterpret_cast<const float4*>(p);
                hi = *reinterpret_cast<const float4*>(p + 4);
            }
            a[m][ks] = cvt8(lo, hi);
        }
    }

    for (int ly = 0; ly < nlayers; ++ly) {
        const float* W = (ly == 0) ? W0 : (ly == 1) ? W1 : W2;
        const float* b = (ly == 0) ? b0 : (ly == 1) ? b1 : b2;
        void*        o = (ly == 0) ? o0 : (ly == 1) ? o1 : o2;

        bf16x8 bf[2][2];  // [n][ks]
        float  bias[2];
        #pragma unroll
        for (int n = 0; n < 2; ++n) {
            const int col = col0 + 16 * n + lr;
            bias[n] = b[col];
            #pragma unroll
            for (int ks = 0; ks < 2; ++ks) {
                const float* p = W + (size_t)col * 64 + ks * 32 + lk;
                const float4 lo = *reinterpret_cast<const float4*>(p);
                const float4 hi = *reinterpret_cast<const float4*>(p + 4);
                bf[n][ks] = cvt8(lo, hi);
            }
        }

        f32x4 acc[2][2];
        #pragma unroll
        for (int m = 0; m < 2; ++m)
            #pragma unroll
            for (int n = 0; n < 2; ++n)
                acc[m][n] = (f32x4){0.f, 0.f, 0.f, 0.f};

        #pragma unroll
        for (int m = 0; m < 2; ++m) {
            #pragma unroll
            for (int n = 0; n < 2; ++n) {
                acc[m][n] = __builtin_amdgcn_mfma_f32_16x16x32_bf16(a[m][0], bf[n][0], acc[m][n], 0, 0, 0);
                acc[m][n] = __builtin_amdgcn_mfma_f32_16x16x32_bf16(a[m][1], bf[n][1], acc[m][n], 0, 0, 0);
            }
        }

        const bool relu = (relu_mask >> ly) & 1;
        const bool b16  = (bf16_mask >> ly) & 1;
        #pragma unroll
        for (int m = 0; m < 2; ++m) {
            #pragma unroll
            for (int r = 0; r < 4; ++r) {
                const int row = row0 + 16 * m + (l >> 4) * 4 + r;
                if (row < nrows) {
                    #pragma unroll
                    for (int n = 0; n < 2; ++n) {
                        const int col = col0 + 16 * n + lr;
                        float v = acc[m][n][r] + bias[n];
                        if (relu) v = fmaxf(v, 0.f);
                        if (b16) ((ushort_t*)o)[(size_t)row * 64 + col] = f2bf(v);
                        else     ((float*)o)[(size_t)row * 64 + col] = v;
                    }
                }
            }
        }
    }
}

// ---------------- bucket pipeline (fixed-capacity segments) ----------------
__global__ __launch_bounds__(256) void init_cursor(int* __restrict__ bcursor)
{
    int i = blockIdx.x * 256 + threadIdx.x;
    if (i < NB) bcursor[i] = i * CAP;
}

// Block-aggregated partition: one global atomic per (block,bucket); contiguous
// per-block sub-segments. pk = (src_global << SHIFT) | dst_local.
__global__ __launch_bounds__(256) void partition_fill(
    const int* __restrict__ efs, const int* __restrict__ efd,
    const int* __restrict__ ebs, const int* __restrict__ ebd,
    const int* __restrict__ ecs, const int* __restrict__ ecd,
    int* __restrict__ bcursor, unsigned* __restrict__ pk)
{
    __shared__ int h[NB];
    __shared__ int base[NB];
    for (int i = threadIdx.x; i < NB; i += 256) h[i] = 0;
    __syncthreads();
    const int e0 = blockIdx.x * PF_CHUNK;
    unsigned pack[16];
    int buck[16], rank[16];
    #pragma unroll
    for (int i = 0; i < 16; ++i) {
        const int e = e0 + i * 256 + threadIdx.x;
        buck[i] = -1;
        if (e < E3) {
            int d, sg;
            if (e < E)          { d = efd[e];         sg = efs[e]; }
            else if (e < 2 * E) { d = ebs[e - E];     sg = NX + ebd[e - E]; }      // '<-': swap
            else                { d = ecd[e - 2 * E]; sg = 2 * NX + ecs[e - 2 * E]; }
            buck[i] = d >> SHIFT;
            pack[i] = ((unsigned)sg << SHIFT) | (unsigned)(d & (BUCK_NODES - 1));
            rank[i] = atomicAdd(&h[buck[i]], 1);
        }
    }
    __syncthreads();
    for (int b = threadIdx.x; b < NB; b += 256)
        base[b] = h[b] ? atomicAdd(&bcursor[b], h[b]) : 0;
    __syncthreads();
    #pragma unroll
    for (int i = 0; i < 16; ++i)
        if (buck[i] >= 0) pk[base[buck[i]] + rank[i]] = pack[i];
}

// One block per bucket: counting sort by dst-local -> srt (global src row ids),
// and per-node (start,count) segments.
__global__ __launch_bounds__(256) void node_sort(
    const int* __restrict__ bcursor, const unsigned* __restrict__ pk,
    int* __restrict__ srt, int2* __restrict__ nodeseg)
{
    __shared__ int cnt[BUCK_NODES];
    __shared__ int cur[BUCK_NODES];
    const int b = blockIdx.x;
    const int s = b * CAP;
    const int t = bcursor[b];
    cnt[threadIdx.x] = 0;
    __syncthreads();
    for (int e = s + threadIdx.x; e < t; e += 256)
        atomicAdd(&cnt[pk[e] & (BUCK_NODES - 1)], 1);
    __syncthreads();
    if (threadIdx.x == 0) {
        int run = s;
        for (int i = 0; i < BUCK_NODES; ++i) { cur[i] = run; run += cnt[i]; }
    }
    __syncthreads();
    const int node = (b << SHIFT) + threadIdx.x;
    const int my_start = cur[threadIdx.x];
    const int my_cnt   = cnt[threadIdx.x];
    __syncthreads();
    if (node < NX) nodeseg[node] = make_int2(my_start, my_cnt);
    for (int e = s + threadIdx.x; e < t; e += 256) {
        const unsigned p = pk[e];
        const int pos = atomicAdd(&cur[p & (BUCK_NODES - 1)], 1);
        srt[pos] = (int)(p >> SHIFT);
    }
}

// One wave per dst node; half-wave q handles edges start+q, start+q+2, ...
// Each lane covers 2 features via packed bf16x2. agg already holds self_x (f32).
__global__ __launch_bounds__(256) void gather_agg_bf16(
    const int2* __restrict__ nodeseg, const int* __restrict__ srt,
    const ushort_t* __restrict__ h_bf, float* __restrict__ agg)
{
    const int wid = (blockIdx.x * 256 + threadIdx.x) >> 6;
    if (wid >= NX) return;
    const int lane = threadIdx.x & 63;
    const int half = lane >> 5;
    const int fl   = lane & 31;
    const int2 seg = nodeseg[wid];
    const int end  = seg.x + seg.y;
    float ax = 0.f, ay = 0.f;
    int e = seg.x + half;
    for (; e + 6 < end; e += 8) {
        const int s0 = srt[e], s1 = srt[e + 2], s2 = srt[e + 4], s3 = srt[e + 6];
        const unsigned u0 = *reinterpret_cast<const unsigned*>(h_bf + (size_t)s0 * 64 + fl * 2);
        const unsigned u1 = *reinterpret_cast<const unsigned*>(h_bf + (size_t)s1 * 64 + fl * 2);
        const unsigned u2 = *reinterpret_cast<const unsigned*>(h_bf + (size_t)s2 * 64 + fl * 2);
        const unsigned u3 = *reinterpret_cast<const unsigned*>(h_bf + (size_t)s3 * 64 + fl * 2);
        ax += __uint_as_float(u0 << 16) + __uint_as_float(u1 << 16)
            + __uint_as_float(u2 << 16) + __uint_as_float(u3 << 16);
        ay += __uint_as_float(u0 & 0xffff0000u) + __uint_as_float(u1 & 0xffff0000u)
            + __uint_as_float(u2 & 0xffff0000u) + __uint_as_float(u3 & 0xffff0000u);
    }
    for (; e < end; e += 2) {
        const unsigned u = *reinterpret_cast<const unsigned*>(h_bf + (size_t)srt[e] * 64 + fl * 2);
        ax += __uint_as_float(u << 16);
        ay += __uint_as_float(u & 0xffff0000u);
    }
    ax += __shfl_xor(ax, 32, 64);
    ay += __shfl_xor(ay, 32, 64);
    if (half == 0) {
        float2* p = reinterpret_cast<float2*>(agg + (size_t)wid * 64) + fl;
        float2 v = *p;
        v.x += ax; v.y += ay;
        *p = v;
    }
}

// fallback: per-edge global atomics on f32 agg, bf16 h
__global__ __launch_bounds__(256) void scatter_edges(
    const int* __restrict__ efs, const int* __restrict__ efd,
    const int* __restrict__ ebs, const int* __restrict__ ebd,
    const int* __restrict__ ecs, const int* __restrict__ ecd,
    const ushort_t* __restrict__ h_all, float* __restrict__ agg)
{
    const int idx  = blockIdx.x * 256 + threadIdx.x;
    const int lane = idx & 63;
    const int e    = idx >> 6;
    if (e >= E3) return;
    int src, dst;
    if (e < E)          { src = efs[e];           dst = efd[e]; }
    else if (e < 2 * E) { src = NX + ebd[e - E];  dst = ebs[e - E]; }
    else                { src = 2 * NX + ecs[e - 2 * E]; dst = ecd[e - 2 * E]; }
    const unsigned u = (unsigned)h_all[(size_t)src * 64 + lane] << 16;
    atomicAdd(&agg[(size_t)dst * 64 + lane], __uint_as_float(u));
}

extern "C" void kernel_launch(void* const* d_in, const int* in_sizes, int n_in,
                              void* d_out, int out_size, void* d_ws, size_t ws_size,
                              hipStream_t stream)
{
    const float* x   = (const float*)d_in[0];
    const float* c   = (const float*)d_in[1];
    const int*   efs = (const int*)d_in[2];
    const int*   efd = (const int*)d_in[3];
    const int*   ebs = (const int*)d_in[4];
    const int*   ebd = (const int*)d_in[5];
    const int*   ecs = (const int*)d_in[6];
    const int*   ecd = (const int*)d_in[7];
    const float* Wx  = (const float*)d_in[8];
    const float* bx  = (const float*)d_in[9];
    const float* Wc  = (const float*)d_in[10];
    const float* bc  = (const float*)d_in[11];
    const float* Wff = (const float*)d_in[12];
    const float* bff = (const float*)d_in[13];
    const float* Wbb = (const float*)d_in[14];
    const float* bbb = (const float*)d_in[15];
    const float* Wcx = (const float*)d_in[16];
    const float* bcx = (const float*)d_in[17];
    const float* Wp  = (const float*)d_in[18];
    const float* bp  = (const float*)d_in[19];

    float* out_x = (float*)d_out;                    // [NX*64]; also agg buffer
    float* out_c = (float*)d_out + (size_t)NX * 64;  // [NC*64]

    ushort_t* h_all = (ushort_t*)d_ws;               // rows: [0,NX)=hff, [NX,2NX)=hbb, [2NX,..)=hcx
    ushort_t* hff = h_all;
    ushort_t* hbb = h_all + (size_t)NX * 64;
    ushort_t* hcx = h_all + (size_t)2 * NX * 64;
    const size_t h_elems = (size_t)(2 * NX + NC) * 64;        // 32MB

    int2* nodeseg = (int2*)(h_all + h_elems);                 // NX
    int*  bcursor = (int*)(nodeseg + NX);                     // NB
    unsigned* pk  = (unsigned*)(bcursor + NB);                // NB*CAP
    int*  srt     = (int*)(pk + (size_t)NB * CAP);            // NB*CAP
    const size_t need_bytes = h_elems * 2 + (size_t)NX * 8 +
                              ((size_t)NB + 2 * (size_t)NB * CAP) * 4;

    // node GEMMs (MFMA): agg=self_x (f32), h tables (bf16)
    fused_linear_mfma<<<(NX + 63) / 64, 256, 0, stream>>>(
        x, NX, Wx, bx, out_x, Wff, bff, hff, Wbb, bbb, hbb, 3, 7, 6);
    fused_linear_mfma<<<(NC + 63) / 64, 256, 0, stream>>>(
        c, NC, Wc, bc, out_c, Wcx, bcx, hcx, nullptr, nullptr, nullptr, 2, 3, 2);

    if (ws_size >= need_bytes) {
        init_cursor<<<(NB + 255) / 256, 256, 0, stream>>>(bcursor);
        partition_fill<<<(E3 + PF_CHUNK - 1) / PF_CHUNK, 256, 0, stream>>>(
            efs, efd, ebs, ebd, ecs, ecd, bcursor, pk);
        node_sort<<<NB, BUCK_NODES, 0, stream>>>(bcursor, pk, srt, nodeseg);
        gather_agg_bf16<<<((size_t)NX * 64 + 255) / 256, 256, 0, stream>>>(
            nodeseg, srt, h_all, out_x);
    } else {
        scatter_edges<<<((size_t)E3 * 64 + 255) / 256, 256, 0, stream>>>(
            efs, efd, ebs, ebd, ecs, ecd, h_all, out_x);
    }

    // pool GEMM in-place on agg -> out_x (f32 in / f32 out)
    fused_linear_mfma<<<(NX + 63) / 64, 256, 0, stream>>>(
        out_x, NX, Wp, bp, out_x, nullptr, nullptr, nullptr, nullptr, nullptr, nullptr, 1, 0, 0);
}

// Round 6
// 192.830 us; speedup vs baseline: 7.2957x; 1.1126x over previous
//
#include <hip/hip_runtime.h>
#include <cstddef>

typedef unsigned short ushort_t;
using f32x4  = __attribute__((ext_vector_type(4))) float;
using bf16x8 = __attribute__((ext_vector_type(8))) short;

static constexpr int NX = 100000;
static constexpr int NC = 50000;
static constexpr int E  = 1000000;
static constexpr int E3 = 3 * E;

static constexpr int SHIFT = 8;                               // 256 dst-nodes per bucket
static constexpr int BUCK_NODES = 1 << SHIFT;
static constexpr int NB = (NX + BUCK_NODES - 1) / BUCK_NODES; // 391
static constexpr int CAP = 8448;                              // mean 7673 + 8.8 sigma
static constexpr int PF_CHUNK = 4096;                         // edges per partition block

__device__ inline ushort_t f2bf(float f) {
    unsigned u = __float_as_uint(f);
    return (ushort_t)((u + 0x7fffu + ((u >> 16) & 1u)) >> 16);   // RNE
}

__device__ inline bf16x8 cvt8(float4 lo, float4 hi) {
    bf16x8 v;
    v[0] = (short)f2bf(lo.x); v[1] = (short)f2bf(lo.y);
    v[2] = (short)f2bf(lo.z); v[3] = (short)f2bf(lo.w);
    v[4] = (short)f2bf(hi.x); v[5] = (short)f2bf(hi.y);
    v[6] = (short)f2bf(hi.z); v[7] = (short)f2bf(hi.w);
    return v;
}

// ---------------- MFMA GEMM: out_l = [relu](in @ W_l^T + b_l), up to 3 layers ----------------
__global__ __launch_bounds__(256) void fused_linear_mfma(
    const float* __restrict__ in, int nrows,
    const float* __restrict__ W0, const float* __restrict__ b0, void* __restrict__ o0,
    const float* __restrict__ W1, const float* __restrict__ b1, void* __restrict__ o1,
    const float* __restrict__ W2, const float* __restrict__ b2, void* __restrict__ o2,
    int nlayers, int relu_mask, int bf16_mask)
{
    const int t   = threadIdx.x;
    const int w   = t >> 6;
    const int l   = t & 63;
    const int lr  = l & 15;
    const int lk  = (l >> 4) * 8;
    const int row0 = blockIdx.x * 64 + (w >> 1) * 32;
    const int col0 = (w & 1) * 32;

    bf16x8 a[2][2];   // [m][ks]
    #pragma unroll
    for (int m = 0; m < 2; ++m) {
        #pragma unroll
        for (int ks = 0; ks < 2; ++ks) {
            const int row = row0 + 16 * m + lr;
            float4 lo = make_float4(0.f, 0.f, 0.f, 0.f), hi = lo;
            if (row < nrows) {
                const float* p = in + (size_t)row * 64 + ks * 32 + lk;
                lo = *reinterpret_cast<const float4*>(p);
                hi = *reinterpret_cast<const float4*>(p + 4);
            }
            a[m][ks] = cvt8(lo, hi);
        }
    }

    for (int ly = 0; ly < nlayers; ++ly) {
        const float* W = (ly == 0) ? W0 : (ly == 1) ? W1 : W2;
        const float* b = (ly == 0) ? b0 : (ly == 1) ? b1 : b2;
        void*        o = (ly == 0) ? o0 : (ly == 1) ? o1 : o2;

        bf16x8 bf[2][2];  // [n][ks]
        float  bias[2];
        #pragma unroll
        for (int n = 0; n < 2; ++n) {
            const int col = col0 + 16 * n + lr;
            bias[n] = b[col];
            #pragma unroll
            for (int ks = 0; ks < 2; ++ks) {
                const float* p = W + (size_t)col * 64 + ks * 32 + lk;
                const float4 lo = *reinterpret_cast<const float4*>(p);
                const float4 hi = *reinterpret_cast<const float4*>(p + 4);
                bf[n][ks] = cvt8(lo, hi);
            }
        }

        f32x4 acc[2][2];
        #pragma unroll
        for (int m = 0; m < 2; ++m)
            #pragma unroll
            for (int n = 0; n < 2; ++n)
                acc[m][n] = (f32x4){0.f, 0.f, 0.f, 0.f};

        #pragma unroll
        for (int m = 0; m < 2; ++m) {
            #pragma unroll
            for (int n = 0; n < 2; ++n) {
                acc[m][n] = __builtin_amdgcn_mfma_f32_16x16x32_bf16(a[m][0], bf[n][0], acc[m][n], 0, 0, 0);
                acc[m][n] = __builtin_amdgcn_mfma_f32_16x16x32_bf16(a[m][1], bf[n][1], acc[m][n], 0, 0, 0);
            }
        }

        const bool relu = (relu_mask >> ly) & 1;
        const bool b16  = (bf16_mask >> ly) & 1;
        #pragma unroll
        for (int m = 0; m < 2; ++m) {
            #pragma unroll
            for (int r = 0; r < 4; ++r) {
                const int row = row0 + 16 * m + (l >> 4) * 4 + r;
                if (row < nrows) {
                    #pragma unroll
                    for (int n = 0; n < 2; ++n) {
                        const int col = col0 + 16 * n + lr;
                        float v = acc[m][n][r] + bias[n];
                        if (relu) v = fmaxf(v, 0.f);
                        if (b16) ((ushort_t*)o)[(size_t)row * 64 + col] = f2bf(v);
                        else     ((float*)o)[(size_t)row * 64 + col] = v;
                    }
                }
            }
        }
    }
}

// ---------------- init: bucket cursors + bf16 copy of Wp ----------------
__global__ __launch_bounds__(256) void init_misc(
    int* __restrict__ bcursor, const float* __restrict__ Wp, ushort_t* __restrict__ wp_bf)
{
    if (blockIdx.x == 0) {
        for (int i = threadIdx.x; i < NB; i += 256) bcursor[i] = i * CAP;
    } else {
        for (int i = threadIdx.x; i < 64 * 64; i += 256) wp_bf[i] = f2bf(Wp[i]);
    }
}

// Block-aggregated partition: one global atomic per (block,bucket); contiguous
// per-block sub-segments. pk = (src_global << SHIFT) | dst_local.
__global__ __launch_bounds__(256) void partition_fill(
    const int* __restrict__ efs, const int* __restrict__ efd,
    const int* __restrict__ ebs, const int* __restrict__ ebd,
    const int* __restrict__ ecs, const int* __restrict__ ecd,
    int* __restrict__ bcursor, unsigned* __restrict__ pk)
{
    __shared__ int h[NB];
    __shared__ int base[NB];
    for (int i = threadIdx.x; i < NB; i += 256) h[i] = 0;
    __syncthreads();
    const int e0 = blockIdx.x * PF_CHUNK;
    unsigned pack[16];
    int buck[16], rank[16];
    #pragma unroll
    for (int i = 0; i < 16; ++i) {
        const int e = e0 + i * 256 + threadIdx.x;
        buck[i] = -1;
        if (e < E3) {
            int d, sg;
            if (e < E)          { d = efd[e];         sg = efs[e]; }
            else if (e < 2 * E) { d = ebs[e - E];     sg = NX + ebd[e - E]; }      // '<-': swap
            else                { d = ecd[e - 2 * E]; sg = 2 * NX + ecs[e - 2 * E]; }
            buck[i] = d >> SHIFT;
            pack[i] = ((unsigned)sg << SHIFT) | (unsigned)(d & (BUCK_NODES - 1));
            rank[i] = atomicAdd(&h[buck[i]], 1);
        }
    }
    __syncthreads();
    for (int b = threadIdx.x; b < NB; b += 256)
        base[b] = h[b] ? atomicAdd(&bcursor[b], h[b]) : 0;
    __syncthreads();
    #pragma unroll
    for (int i = 0; i < 16; ++i)
        if (buck[i] >= 0) pk[base[buck[i]] + rank[i]] = pack[i];
}

// One block per bucket: counting sort by dst-local -> srt (global src row ids),
// and per-node (start,count) segments.
__global__ __launch_bounds__(256) void node_sort(
    const int* __restrict__ bcursor, const unsigned* __restrict__ pk,
    int* __restrict__ srt, int2* __restrict__ nodeseg)
{
    __shared__ int cnt[BUCK_NODES];
    __shared__ int cur[BUCK_NODES];
    const int b = blockIdx.x;
    const int s = b * CAP;
    const int t = bcursor[b];
    cnt[threadIdx.x] = 0;
    __syncthreads();
    for (int e = s + threadIdx.x; e < t; e += 256)
        atomicAdd(&cnt[pk[e] & (BUCK_NODES - 1)], 1);
    __syncthreads();
    if (threadIdx.x == 0) {
        int run = s;
        for (int i = 0; i < BUCK_NODES; ++i) { cur[i] = run; run += cnt[i]; }
    }
    __syncthreads();
    const int node = (b << SHIFT) + threadIdx.x;
    const int my_start = cur[threadIdx.x];
    const int my_cnt   = cnt[threadIdx.x];
    __syncthreads();
    if (node < NX) nodeseg[node] = make_int2(my_start, my_cnt);
    for (int e = s + threadIdx.x; e < t; e += 256) {
        const unsigned p = pk[e];
        const int pos = atomicAdd(&cur[p & (BUCK_NODES - 1)], 1);
        srt[pos] = (int)(p >> SHIFT);
    }
}

// ---------------- fused gather + pool ----------------
// Block = 16 nodes, 4 waves x 4 nodes. Per node: half-wave q sums edges
// start+q, start+q+2, ... (2 bf16 features/lane). Self row added on half 0.
// Rows deposited bf16 into LDS tile; pool = 2 MFMAs per wave (N-tile = w*16).
__global__ __launch_bounds__(256) void gather_pool_mfma(
    const int2* __restrict__ nodeseg, const int* __restrict__ srt,
    const ushort_t* __restrict__ h_bf, const ushort_t* __restrict__ h_self,
    const ushort_t* __restrict__ wp_bf, const float* __restrict__ bp,
    float* __restrict__ out_x)
{
    __shared__ ushort_t agg_lds[16 * 72];   // stride 72 bf16 = 144 B (bank-safe, 16B-aligned)
    __shared__ ushort_t wp_lds[64 * 72];
    const int t = threadIdx.x;

    // stage Wp (bf16) into padded LDS
    {
        const int j  = t >> 2;
        const int c0 = (t & 3) * 16;
        const uint4 v0 = *reinterpret_cast<const uint4*>(wp_bf + j * 64 + c0);
        const uint4 v1 = *reinterpret_cast<const uint4*>(wp_bf + j * 64 + c0 + 8);
        *reinterpret_cast<uint4*>(&wp_lds[j * 72 + c0]) = v0;
        *reinterpret_cast<uint4*>(&wp_lds[j * 72 + c0 + 8]) = v1;
    }

    const int w    = t >> 6;
    const int lane = t & 63;
    const int half = lane >> 5;
    const int fl   = lane & 31;
    const int node0 = blockIdx.x * 16;

    for (int i = 0; i < 4; ++i) {
        const int node = node0 + w * 4 + i;
        const int2 seg = nodeseg[node];
        const int end  = seg.x + seg.y;
        float ax = 0.f, ay = 0.f;
        if (half == 0) {
            const unsigned u = *reinterpret_cast<const unsigned*>(h_self + (size_t)node * 64 + fl * 2);
            ax = __uint_as_float(u << 16);
            ay = __uint_as_float(u & 0xffff0000u);
        }
        int e = seg.x + half;
        for (; e + 14 < end; e += 16) {
            unsigned u[8];
            #pragma unroll
            for (int q = 0; q < 8; ++q) {
                const int sidx = srt[e + 2 * q];
                u[q] = *reinterpret_cast<const unsigned*>(h_bf + (size_t)sidx * 64 + fl * 2);
            }
            #pragma unroll
            for (int q = 0; q < 8; ++q) {
                ax += __uint_as_float(u[q] << 16);
                ay += __uint_as_float(u[q] & 0xffff0000u);
            }
        }
        for (; e + 6 < end; e += 8) {
            unsigned u[4];
            #pragma unroll
            for (int q = 0; q < 4; ++q) {
                const int sidx = srt[e + 2 * q];
                u[q] = *reinterpret_cast<const unsigned*>(h_bf + (size_t)sidx * 64 + fl * 2);
            }
            #pragma unroll
            for (int q = 0; q < 4; ++q) {
                ax += __uint_as_float(u[q] << 16);
                ay += __uint_as_float(u[q] & 0xffff0000u);
            }
        }
        for (; e < end; e += 2) {
            const unsigned u = *reinterpret_cast<const unsigned*>(h_bf + (size_t)srt[e] * 64 + fl * 2);
            ax += __uint_as_float(u << 16);
            ay += __uint_as_float(u & 0xffff0000u);
        }
        ax += __shfl_xor(ax, 32);
        ay += __shfl_xor(ay, 32);
        if (half == 0) {
            const unsigned packed = ((unsigned)f2bf(ay) << 16) | (unsigned)f2bf(ax);
            *reinterpret_cast<unsigned*>(&agg_lds[(w * 4 + i) * 72 + fl * 2]) = packed;
        }
    }
    __syncthreads();

    // pool: wave w -> cols w*16 .. w*16+15, rows 0..15
    const int lr = lane & 15;
    const int q4 = lane >> 4;
    bf16x8 afrag0 = *reinterpret_cast<const bf16x8*>(&agg_lds[lr * 72 + q4 * 8]);
    bf16x8 afrag1 = *reinterpret_cast<const bf16x8*>(&agg_lds[lr * 72 + 32 + q4 * 8]);
    bf16x8 bfrag0 = *reinterpret_cast<const bf16x8*>(&wp_lds[(w * 16 + lr) * 72 + q4 * 8]);
    bf16x8 bfrag1 = *reinterpret_cast<const bf16x8*>(&wp_lds[(w * 16 + lr) * 72 + 32 + q4 * 8]);
    f32x4 acc = (f32x4){0.f, 0.f, 0.f, 0.f};
    acc = __builtin_amdgcn_mfma_f32_16x16x32_bf16(afrag0, bfrag0, acc, 0, 0, 0);
    acc = __builtin_amdgcn_mfma_f32_16x16x32_bf16(afrag1, bfrag1, acc, 0, 0, 0);

    const int col = w * 16 + lr;
    const float bias = bp[col];
    #pragma unroll
    for (int r = 0; r < 4; ++r) {
        const int row = q4 * 4 + r;
        out_x[(size_t)(node0 + row) * 64 + col] = acc[r] + bias;
    }
}

// fallback: per-edge global atomics on f32 agg, bf16 h
__global__ __launch_bounds__(256) void scatter_edges(
    const int* __restrict__ efs, const int* __restrict__ efd,
    const int* __restrict__ ebs, const int* __restrict__ ebd,
    const int* __restrict__ ecs, const int* __restrict__ ecd,
    const ushort_t* __restrict__ h_all, float* __restrict__ agg)
{
    const int idx  = blockIdx.x * 256 + threadIdx.x;
    const int lane = idx & 63;
    const int e    = idx >> 6;
    if (e >= E3) return;
    int src, dst;
    if (e < E)          { src = efs[e];           dst = efd[e]; }
    else if (e < 2 * E) { src = NX + ebd[e - E];  dst = ebs[e - E]; }
    else                { src = 2 * NX + ecs[e - 2 * E]; dst = ecd[e - 2 * E]; }
    const unsigned u = (unsigned)h_all[(size_t)src * 64 + lane] << 16;
    atomicAdd(&agg[(size_t)dst * 64 + lane], __uint_as_float(u));
}

extern "C" void kernel_launch(void* const* d_in, const int* in_sizes, int n_in,
                              void* d_out, int out_size, void* d_ws, size_t ws_size,
                              hipStream_t stream)
{
    const float* x   = (const float*)d_in[0];
    const float* c   = (const float*)d_in[1];
    const int*   efs = (const int*)d_in[2];
    const int*   efd = (const int*)d_in[3];
    const int*   ebs = (const int*)d_in[4];
    const int*   ebd = (const int*)d_in[5];
    const int*   ecs = (const int*)d_in[6];
    const int*   ecd = (const int*)d_in[7];
    const float* Wx  = (const float*)d_in[8];
    const float* bx  = (const float*)d_in[9];
    const float* Wc  = (const float*)d_in[10];
    const float* bc  = (const float*)d_in[11];
    const float* Wff = (const float*)d_in[12];
    const float* bff = (const float*)d_in[13];
    const float* Wbb = (const float*)d_in[14];
    const float* bbb = (const float*)d_in[15];
    const float* Wcx = (const float*)d_in[16];
    const float* bcx = (const float*)d_in[17];
    const float* Wp  = (const float*)d_in[18];
    const float* bp  = (const float*)d_in[19];

    float* out_x = (float*)d_out;                    // [NX*64]
    float* out_c = (float*)d_out + (size_t)NX * 64;  // [NC*64]

    // ws layout: bf16 h tables (ff, bb, cx, self), wp_bf, nodeseg, bcursor, pk, srt
    ushort_t* h_all  = (ushort_t*)d_ws;
    ushort_t* hff    = h_all;
    ushort_t* hbb    = h_all + (size_t)NX * 64;
    ushort_t* hcx    = h_all + (size_t)2 * NX * 64;
    ushort_t* h_self = h_all + (size_t)(2 * NX + NC) * 64;
    const size_t h_elems = (size_t)(3 * NX + NC) * 64;        // 44.8 MB

    ushort_t* wp_bf  = h_all + h_elems;                       // 64*64
    int2* nodeseg = (int2*)(wp_bf + 64 * 64);                 // NX
    int*  bcursor = (int*)(nodeseg + NX);                     // NB
    unsigned* pk  = (unsigned*)(bcursor + NB);                // NB*CAP
    int*  srt     = (int*)(pk + (size_t)NB * CAP);            // NB*CAP
    const size_t need_bytes = (h_elems + 64 * 64) * 2 + (size_t)NX * 8 +
                              ((size_t)NB + 2 * (size_t)NB * CAP) * 4;

    if (ws_size >= need_bytes) {
        // GEMMs: all h tables bf16 (self, ff, bb) / (out_c f32, cx bf16)
        fused_linear_mfma<<<(NX + 63) / 64, 256, 0, stream>>>(
            x, NX, Wx, bx, h_self, Wff, bff, hff, Wbb, bbb, hbb, 3, 7, 7);
        fused_linear_mfma<<<(NC + 63) / 64, 256, 0, stream>>>(
            c, NC, Wc, bc, out_c, Wcx, bcx, hcx, nullptr, nullptr, nullptr, 2, 3, 2);
        init_misc<<<2, 256, 0, stream>>>(bcursor, Wp, wp_bf);
        partition_fill<<<(E3 + PF_CHUNK - 1) / PF_CHUNK, 256, 0, stream>>>(
            efs, efd, ebs, ebd, ecs, ecd, bcursor, pk);
        node_sort<<<NB, BUCK_NODES, 0, stream>>>(bcursor, pk, srt, nodeseg);
        gather_pool_mfma<<<NX / 16, 256, 0, stream>>>(
            nodeseg, srt, h_all, h_self, wp_bf, bp, out_x);
    } else {
        // fallback: self_x f32 into out_x, per-edge atomics, standalone pool
        fused_linear_mfma<<<(NX + 63) / 64, 256, 0, stream>>>(
            x, NX, Wx, bx, out_x, Wff, bff, hff, Wbb, bbb, hbb, 3, 7, 6);
        fused_linear_mfma<<<(NC + 63) / 64, 256, 0, stream>>>(
            c, NC, Wc, bc, out_c, Wcx, bcx, hcx, nullptr, nullptr, nullptr, 2, 3, 2);
        scatter_edges<<<((size_t)E3 * 64 + 255) / 256, 256, 0, stream>>>(
            efs, efd, ebs, ebd, ecs, ecd, h_all, out_x);
        fused_linear_mfma<<<(NX + 63) / 64, 256, 0, stream>>>(
            out_x, NX, Wp, bp, out_x, nullptr, nullptr, nullptr, nullptr, nullptr, nullptr, 1, 0, 0);
    }
}

// Round 7
// 151.324 us; speedup vs baseline: 9.2969x; 1.2743x over previous
//
#include <hip/hip_runtime.h>
#include <cstddef>

typedef unsigned short ushort_t;
using f32x4  = __attribute__((ext_vector_type(4))) float;
using bf16x8 = __attribute__((ext_vector_type(8))) short;

static constexpr int NX = 100000;
static constexpr int NC = 50000;
static constexpr int E  = 1000000;
static constexpr int E3 = 3 * E;

static constexpr int SHIFT = 6;                     // 64 dst-nodes per bucket
static constexpr int BN = 1 << SHIFT;               // 64
static constexpr int NB = (NX + BN - 1) / BN;       // 1563
static constexpr int CAP = 2304;                    // mean 1920 + 8.8 sigma
static constexpr int PF_CHUNK = 4096;               // edges per partition block
static constexpr int NXT = (NX + 63) / 64;          // 1563
static constexpr int NCT = (NC + 63) / 64;          // 782

__device__ inline ushort_t f2bf(float f) {
    unsigned u = __float_as_uint(f);
    return (ushort_t)((u + 0x7fffu + ((u >> 16) & 1u)) >> 16);   // RNE
}

__device__ inline bf16x8 cvt8(float4 lo, float4 hi) {
    bf16x8 v;
    v[0] = (short)f2bf(lo.x); v[1] = (short)f2bf(lo.y);
    v[2] = (short)f2bf(lo.z); v[3] = (short)f2bf(lo.w);
    v[4] = (short)f2bf(hi.x); v[5] = (short)f2bf(hi.y);
    v[6] = (short)f2bf(hi.z); v[7] = (short)f2bf(hi.w);
    return v;
}

__device__ inline float bfl(unsigned u) { return __uint_as_float(u << 16); }
__device__ inline float bfh(unsigned u) { return __uint_as_float(u & 0xffff0000u); }

// ---------------- MFMA GEMM tile body: out_l = [relu](in @ W_l^T + b_l), up to 3 layers ----
// A-frag: lane l, reg r -> in[row0+16m+(l&15)][ks*32+(l>>4)*8+r]
// B-frag: lane l, reg r -> W [col0+16n+(l&15)][ks*32+(l>>4)*8+r]
// C/D   : col = l&15, row = (l>>4)*4 + reg
__device__ __forceinline__ void gemm_tile(
    const float* __restrict__ in, int nrows, int tile_row0,
    const float* __restrict__ W0, const float* __restrict__ b0, void* __restrict__ o0,
    const float* __restrict__ W1, const float* __restrict__ b1, void* __restrict__ o1,
    const float* __restrict__ W2, const float* __restrict__ b2, void* __restrict__ o2,
    int nlayers, int relu_mask, int bf16_mask)
{
    const int t   = threadIdx.x;
    const int w   = t >> 6;
    const int l   = t & 63;
    const int lr  = l & 15;
    const int lk  = (l >> 4) * 8;
    const int row0 = tile_row0 + (w >> 1) * 32;
    const int col0 = (w & 1) * 32;

    bf16x8 a[2][2];   // [m][ks]
    #pragma unroll
    for (int m = 0; m < 2; ++m) {
        #pragma unroll
        for (int ks = 0; ks < 2; ++ks) {
            const int row = row0 + 16 * m + lr;
            float4 lo = make_float4(0.f, 0.f, 0.f, 0.f), hi = lo;
            if (row < nrows) {
                const float* p = in + (size_t)row * 64 + ks * 32 + lk;
                lo = *reinterpret_cast<const float4*>(p);
                hi = *reinterpret_cast<const float4*>(p + 4);
            }
            a[m][ks] = cvt8(lo, hi);
        }
    }

    for (int ly = 0; ly < nlayers; ++ly) {
        const float* W = (ly == 0) ? W0 : (ly == 1) ? W1 : W2;
        const float* b = (ly == 0) ? b0 : (ly == 1) ? b1 : b2;
        void*        o = (ly == 0) ? o0 : (ly == 1) ? o1 : o2;

        bf16x8 bf[2][2];  // [n][ks]
        float  bias[2];
        #pragma unroll
        for (int n = 0; n < 2; ++n) {
            const int col = col0 + 16 * n + lr;
            bias[n] = b[col];
            #pragma unroll
            for (int ks = 0; ks < 2; ++ks) {
                const float* p = W + (size_t)col * 64 + ks * 32 + lk;
                const float4 lo = *reinterpret_cast<const float4*>(p);
                const float4 hi = *reinterpret_cast<const float4*>(p + 4);
                bf[n][ks] = cvt8(lo, hi);
            }
        }

        f32x4 acc[2][2];
        #pragma unroll
        for (int m = 0; m < 2; ++m)
            #pragma unroll
            for (int n = 0; n < 2; ++n)
                acc[m][n] = (f32x4){0.f, 0.f, 0.f, 0.f};

        #pragma unroll
        for (int m = 0; m < 2; ++m) {
            #pragma unroll
            for (int n = 0; n < 2; ++n) {
                acc[m][n] = __builtin_amdgcn_mfma_f32_16x16x32_bf16(a[m][0], bf[n][0], acc[m][n], 0, 0, 0);
                acc[m][n] = __builtin_amdgcn_mfma_f32_16x16x32_bf16(a[m][1], bf[n][1], acc[m][n], 0, 0, 0);
            }
        }

        const bool relu = (relu_mask >> ly) & 1;
        const bool b16  = (bf16_mask >> ly) & 1;
        #pragma unroll
        for (int m = 0; m < 2; ++m) {
            #pragma unroll
            for (int r = 0; r < 4; ++r) {
                const int row = row0 + 16 * m + (l >> 4) * 4 + r;
                if (row < nrows) {
                    #pragma unroll
                    for (int n = 0; n < 2; ++n) {
                        const int col = col0 + 16 * n + lr;
                        float v = acc[m][n][r] + bias[n];
                        if (relu) v = fmaxf(v, 0.f);
                        if (b16) ((ushort_t*)o)[(size_t)row * 64 + col] = f2bf(v);
                        else     ((float*)o)[(size_t)row * 64 + col] = v;
                    }
                }
            }
        }
    }
}

// combined: NX tiles (x -> h_self, hff, hbb) + NC tiles (c -> out_c, hcx) + bcursor init
__global__ __launch_bounds__(256) void gemm_all(
    const float* __restrict__ x, const float* __restrict__ c,
    const float* __restrict__ Wx, const float* __restrict__ bx, ushort_t* __restrict__ h_self,
    const float* __restrict__ Wff, const float* __restrict__ bff, ushort_t* __restrict__ hff,
    const float* __restrict__ Wbb, const float* __restrict__ bbb, ushort_t* __restrict__ hbb,
    const float* __restrict__ Wc, const float* __restrict__ bc, float* __restrict__ out_c,
    const float* __restrict__ Wcx, const float* __restrict__ bcx, ushort_t* __restrict__ hcx,
    int* __restrict__ bcursor)
{
    const int b = blockIdx.x;
    if (b < NXT) {
        gemm_tile(x, NX, b * 64, Wx, bx, h_self, Wff, bff, hff, Wbb, bbb, hbb, 3, 7, 7);
    } else if (b < NXT + NCT) {
        gemm_tile(c, NC, (b - NXT) * 64, Wc, bc, out_c, Wcx, bcx, hcx,
                  nullptr, nullptr, nullptr, 2, 3, 2);
    } else {
        for (int i = threadIdx.x; i < NB; i += 256) bcursor[i] = i * CAP;
    }
}

// standalone GEMM (fallback path)
__global__ __launch_bounds__(256) void fused_linear_mfma(
    const float* __restrict__ in, int nrows,
    const float* __restrict__ W0, const float* __restrict__ b0, void* __restrict__ o0,
    const float* __restrict__ W1, const float* __restrict__ b1, void* __restrict__ o1,
    const float* __restrict__ W2, const float* __restrict__ b2, void* __restrict__ o2,
    int nlayers, int relu_mask, int bf16_mask)
{
    gemm_tile(in, nrows, blockIdx.x * 64, W0, b0, o0, W1, b1, o1, W2, b2, o2,
              nlayers, relu_mask, bf16_mask);
}

// Block-aggregated partition: one global atomic per (block,bucket); contiguous
// per-block sub-segments. pk = (src_global << SHIFT) | dst_local.
__global__ __launch_bounds__(256) void partition_fill(
    const int* __restrict__ efs, const int* __restrict__ efd,
    const int* __restrict__ ebs, const int* __restrict__ ebd,
    const int* __restrict__ ecs, const int* __restrict__ ecd,
    int* __restrict__ bcursor, unsigned* __restrict__ pk)
{
    __shared__ int h[NB];
    __shared__ int base[NB];
    for (int i = threadIdx.x; i < NB; i += 256) h[i] = 0;
    __syncthreads();
    const int e0 = blockIdx.x * PF_CHUNK;
    unsigned pack[16];
    int buck[16], rank[16];
    #pragma unroll
    for (int i = 0; i < 16; ++i) {
        const int e = e0 + i * 256 + threadIdx.x;
        buck[i] = -1;
        if (e < E3) {
            int d, sg;
            if (e < E)          { d = efd[e];         sg = efs[e]; }
            else if (e < 2 * E) { d = ebs[e - E];     sg = NX + ebd[e - E]; }      // '<-': swap
            else                { d = ecd[e - 2 * E]; sg = 2 * NX + ecs[e - 2 * E]; }
            buck[i] = d >> SHIFT;
            pack[i] = ((unsigned)sg << SHIFT) | (unsigned)(d & (BN - 1));
            rank[i] = atomicAdd(&h[buck[i]], 1);
        }
    }
    __syncthreads();
    for (int b = threadIdx.x; b < NB; b += 256)
        base[b] = h[b] ? atomicAdd(&bcursor[b], h[b]) : 0;
    __syncthreads();
    #pragma unroll
    for (int i = 0; i < 16; ++i)
        if (buck[i] >= 0) pk[base[buck[i]] + rank[i]] = pack[i];
}

// One block per 64-node bucket: LDS counting sort -> srt (byte offsets into h_all),
// quarter-wave gather (16 lanes x dwordx2 per edge), LDS bf16 agg tile, pool MFMA.
__global__ __launch_bounds__(256) void sort_gather_pool(
    const int* __restrict__ bcursor, const unsigned* __restrict__ pk,
    const ushort_t* __restrict__ h_all, const ushort_t* __restrict__ h_self,
    const float* __restrict__ Wp, const float* __restrict__ bp,
    float* __restrict__ out_x)
{
    __shared__ unsigned srt[CAP];
    __shared__ int cnt[BN], nstart[BN], cur[BN];
    __shared__ ushort_t agg_lds[BN * 72];   // row stride 144 B

    const int b = blockIdx.x;
    const int t = threadIdx.x;
    const int s = b * CAP;
    int tend = bcursor[b];
    if (tend > s + CAP) tend = s + CAP;

    if (t < BN) cnt[t] = 0;
    __syncthreads();
    for (int e = s + t; e < tend; e += 256)
        atomicAdd(&cnt[pk[e] & (BN - 1)], 1);
    __syncthreads();
    if (t < BN) {                         // wave 0: shfl inclusive scan over 64
        const int v = cnt[t];
        int xs = v;
        #pragma unroll
        for (int d = 1; d < BN; d <<= 1) {
            const int y = __shfl_up(xs, d, 64);
            if (t >= d) xs += y;
        }
        nstart[t] = xs - v;
        cur[t]    = xs - v;
    }
    __syncthreads();
    for (int e = s + t; e < tend; e += 256) {
        const unsigned p = pk[e];
        const int pos = atomicAdd(&cur[p & (BN - 1)], 1);
        srt[pos] = (p & ~(unsigned)(BN - 1)) << 1;   // src_global * 128 (byte offset)
    }
    __syncthreads();

    const int w    = t >> 6;
    const int lane = t & 63;
    const int q    = lane >> 4;          // quarter 0..3
    const int fl   = lane & 15;          // feature group: features fl*4..fl*4+3
    const unsigned foff = fl * 8;        // byte offset within 128B row
    const int node0 = b * BN;
    const char* hb = reinterpret_cast<const char*>(h_all);
    const char* hs = reinterpret_cast<const char*>(h_self);

    for (int i = 0; i < 16; ++i) {
        const int nl   = w * 16 + i;
        const int node = node0 + nl;
        const int start = nstart[nl];
        const int count = cnt[nl];
        float a0 = 0.f, a1 = 0.f, a2 = 0.f, a3 = 0.f;
        if (q == 0 && node < NX) {
            const uint2 u = *reinterpret_cast<const uint2*>(hs + (size_t)node * 128 + foff);
            a0 = bfl(u.x); a1 = bfh(u.x); a2 = bfl(u.y); a3 = bfh(u.y);
        }
        int e = q;
        for (; e + 12 < count; e += 16) {
            const unsigned o0 = srt[start + e]      + foff;
            const unsigned o1 = srt[start + e + 4]  + foff;
            const unsigned o2 = srt[start + e + 8]  + foff;
            const unsigned o3 = srt[start + e + 12] + foff;
            const uint2 u0 = *reinterpret_cast<const uint2*>(hb + o0);
            const uint2 u1 = *reinterpret_cast<const uint2*>(hb + o1);
            const uint2 u2 = *reinterpret_cast<const uint2*>(hb + o2);
            const uint2 u3 = *reinterpret_cast<const uint2*>(hb + o3);
            a0 += bfl(u0.x) + bfl(u1.x) + bfl(u2.x) + bfl(u3.x);
            a1 += bfh(u0.x) + bfh(u1.x) + bfh(u2.x) + bfh(u3.x);
            a2 += bfl(u0.y) + bfl(u1.y) + bfl(u2.y) + bfl(u3.y);
            a3 += bfh(u0.y) + bfh(u1.y) + bfh(u2.y) + bfh(u3.y);
        }
        for (; e < count; e += 4) {
            const uint2 u = *reinterpret_cast<const uint2*>(hb + (srt[start + e] + foff));
            a0 += bfl(u.x); a1 += bfh(u.x); a2 += bfl(u.y); a3 += bfh(u.y);
        }
        a0 += __shfl_xor(a0, 16); a0 += __shfl_xor(a0, 32);
        a1 += __shfl_xor(a1, 16); a1 += __shfl_xor(a1, 32);
        a2 += __shfl_xor(a2, 16); a2 += __shfl_xor(a2, 32);
        a3 += __shfl_xor(a3, 16); a3 += __shfl_xor(a3, 32);
        if (q == 0) {
            uint2 pck;
            pck.x = ((unsigned)f2bf(a1) << 16) | (unsigned)f2bf(a0);
            pck.y = ((unsigned)f2bf(a3) << 16) | (unsigned)f2bf(a2);
            *reinterpret_cast<uint2*>(&agg_lds[nl * 72 + fl * 4]) = pck;
        }
    }
    __syncthreads();

    // pool: wave w -> cols w*16..w*16+15 over all 64 rows (4 row-tiles x 2 MFMA)
    const int lr = lane & 15, q4 = lane >> 4;
    const float* wrow = Wp + (size_t)(w * 16 + lr) * 64;
    const bf16x8 bf0 = cvt8(*reinterpret_cast<const float4*>(wrow + q4 * 8),
                            *reinterpret_cast<const float4*>(wrow + q4 * 8 + 4));
    const bf16x8 bf1 = cvt8(*reinterpret_cast<const float4*>(wrow + 32 + q4 * 8),
                            *reinterpret_cast<const float4*>(wrow + 32 + q4 * 8 + 4));
    const float bias = bp[w * 16 + lr];
    #pragma unroll
    for (int rb = 0; rb < 4; ++rb) {
        const bf16x8 af0 = *reinterpret_cast<const bf16x8*>(&agg_lds[(rb * 16 + lr) * 72 + q4 * 8]);
        const bf16x8 af1 = *reinterpret_cast<const bf16x8*>(&agg_lds[(rb * 16 + lr) * 72 + 32 + q4 * 8]);
        f32x4 acc = (f32x4){0.f, 0.f, 0.f, 0.f};
        acc = __builtin_amdgcn_mfma_f32_16x16x32_bf16(af0, bf0, acc, 0, 0, 0);
        acc = __builtin_amdgcn_mfma_f32_16x16x32_bf16(af1, bf1, acc, 0, 0, 0);
        #pragma unroll
        for (int r = 0; r < 4; ++r) {
            const int row = node0 + rb * 16 + q4 * 4 + r;
            if (row < NX)
                out_x[(size_t)row * 64 + w * 16 + lr] = acc[r] + bias;
        }
    }
}

// fallback: per-edge global atomics on f32 agg, bf16 h
__global__ __launch_bounds__(256) void scatter_edges(
    const int* __restrict__ efs, const int* __restrict__ efd,
    const int* __restrict__ ebs, const int* __restrict__ ebd,
    const int* __restrict__ ecs, const int* __restrict__ ecd,
    const ushort_t* __restrict__ h_all, float* __restrict__ agg)
{
    const int idx  = blockIdx.x * 256 + threadIdx.x;
    const int lane = idx & 63;
    const int e    = idx >> 6;
    if (e >= E3) return;
    int src, dst;
    if (e < E)          { src = efs[e];           dst = efd[e]; }
    else if (e < 2 * E) { src = NX + ebd[e - E];  dst = ebs[e - E]; }
    else                { src = 2 * NX + ecs[e - 2 * E]; dst = ecd[e - 2 * E]; }
    const unsigned u = (unsigned)h_all[(size_t)src * 64 + lane] << 16;
    atomicAdd(&agg[(size_t)dst * 64 + lane], __uint_as_float(u));
}

extern "C" void kernel_launch(void* const* d_in, const int* in_sizes, int n_in,
                              void* d_out, int out_size, void* d_ws, size_t ws_size,
                              hipStream_t stream)
{
    const float* x   = (const float*)d_in[0];
    const float* c   = (const float*)d_in[1];
    const int*   efs = (const int*)d_in[2];
    const int*   efd = (const int*)d_in[3];
    const int*   ebs = (const int*)d_in[4];
    const int*   ebd = (const int*)d_in[5];
    const int*   ecs = (const int*)d_in[6];
    const int*   ecd = (const int*)d_in[7];
    const float* Wx  = (const float*)d_in[8];
    const float* bx  = (const float*)d_in[9];
    const float* Wc  = (const float*)d_in[10];
    const float* bc  = (const float*)d_in[11];
    const float* Wff = (const float*)d_in[12];
    const float* bff = (const float*)d_in[13];
    const float* Wbb = (const float*)d_in[14];
    const float* bbb = (const float*)d_in[15];
    const float* Wcx = (const float*)d_in[16];
    const float* bcx = (const float*)d_in[17];
    const float* Wp  = (const float*)d_in[18];
    const float* bp  = (const float*)d_in[19];

    float* out_x = (float*)d_out;                    // [NX*64]
    float* out_c = (float*)d_out + (size_t)NX * 64;  // [NC*64]

    // ws layout: bf16 h tables (ff, bb, cx, self), bcursor, pk
    ushort_t* h_all  = (ushort_t*)d_ws;
    ushort_t* hff    = h_all;
    ushort_t* hbb    = h_all + (size_t)NX * 64;
    ushort_t* hcx    = h_all + (size_t)2 * NX * 64;
    ushort_t* h_self = h_all + (size_t)(2 * NX + NC) * 64;
    const size_t h_elems = (size_t)(3 * NX + NC) * 64;        // 44.8 MB

    int* bcursor = (int*)(h_all + h_elems);                   // NB
    unsigned* pk = (unsigned*)(bcursor + NB);                 // NB*CAP = 14.4 MB
    const size_t need_bytes = h_elems * 2 + (size_t)NB * 4 + (size_t)NB * CAP * 4;

    if (ws_size >= need_bytes) {
        gemm_all<<<NXT + NCT + 1, 256, 0, stream>>>(
            x, c, Wx, bx, h_self, Wff, bff, hff, Wbb, bbb, hbb,
            Wc, bc, out_c, Wcx, bcx, hcx, bcursor);
        partition_fill<<<(E3 + PF_CHUNK - 1) / PF_CHUNK, 256, 0, stream>>>(
            efs, efd, ebs, ebd, ecs, ecd, bcursor, pk);
        sort_gather_pool<<<NB, 256, 0, stream>>>(
            bcursor, pk, h_all, h_self, Wp, bp, out_x);
    } else {
        // fallback: self_x f32 into out_x, per-edge atomics, standalone pool
        fused_linear_mfma<<<NXT, 256, 0, stream>>>(
            x, NX, Wx, bx, out_x, Wff, bff, hff, Wbb, bbb, hbb, 3, 7, 6);
        fused_linear_mfma<<<NCT, 256, 0, stream>>>(
            c, NC, Wc, bc, out_c, Wcx, bcx, hcx, nullptr, nullptr, nullptr, 2, 3, 2);
        scatter_edges<<<((size_t)E3 * 64 + 255) / 256, 256, 0, stream>>>(
            efs, efd, ebs, ebd, ecs, ecd, h_all, out_x);
        fused_linear_mfma<<<NXT, 256, 0, stream>>>(
            out_x, NX, Wp, bp, out_x, nullptr, nullptr, nullptr, nullptr, nullptr, nullptr, 1, 0, 0);
    }
}